// Round 15
// baseline (775.107 us; speedup 1.0000x reference)
//
#include <hip/hip_runtime.h>
#include <math.h>

#define NCB 4
#define KC 256
#define DIM 64
#define NTOK (64*4096)            // 262144 tokens
#define TPB 512
#define TOKB 128                  // tokens per block
#define HALF 128                  // codes staged per half
#define MGRID (NTOK/TOKB)         // 2048 blocks

// ---- workspace byte offsets ----
#define WS_C     0            // 4*256*4   = 4096   (np-exact ||e||^2, f32)
#define WS_P     4096         // 256*64*4  = 65536  (semantic pred table)
#define WS_PVQ   69632        // 2048*4 = 8192
#define WS_PSEM  77824        // 2048*4 = 8192

#define ESTRIDE 68            // e_lds row stride in floats (bank decorrelation)

// np pairwise-8 sum of fl(r*r) (separate mul, NO fma)
#define ROWSQ(rr, A) { \
  float p0=rr[0]*rr[0], p1=rr[1]*rr[1], p2=rr[2]*rr[2], p3=rr[3]*rr[3]; \
  float p4=rr[4]*rr[4], p5=rr[5]*rr[5], p6=rr[6]*rr[6], p7=rr[7]*rr[7]; \
  _Pragma("unroll") \
  for (int m_ = 1; m_ < 8; ++m_) { \
    float s0=rr[8*m_+0]*rr[8*m_+0]; p0=p0+s0; float s1=rr[8*m_+1]*rr[8*m_+1]; p1=p1+s1; \
    float s2=rr[8*m_+2]*rr[8*m_+2]; p2=p2+s2; float s3=rr[8*m_+3]*rr[8*m_+3]; p3=p3+s3; \
    float s4=rr[8*m_+4]*rr[8*m_+4]; p4=p4+s4; float s5=rr[8*m_+5]*rr[8*m_+5]; p5=p5+s5; \
    float s6=rr[8*m_+6]*rr[8*m_+6]; p6=p6+s6; float s7=rr[8*m_+7]*rr[8*m_+7]; p7=p7+s7; \
  } \
  A = ((p0+p1) + (p2+p3)) + ((p4+p5) + (p6+p7)); }

// =====================================================================
// Kernel P: np-exact C tables (pairwise-8 sum of e^2) + semantic table
// =====================================================================
__global__ __launch_bounds__(256) void precompute_kernel(
    const float* __restrict__ E,
    const float* __restrict__ W1, const float* __restrict__ b1,
    const float* __restrict__ W2, const float* __restrict__ b2,
    float* __restrict__ Cnp, float* __restrict__ P) {
#pragma clang fp contract(off)
    const int t = threadIdx.x;
    if (blockIdx.x == 0) {
        for (int i = 0; i < NCB; ++i) {
            const float* row = E + (size_t)(i*KC + t)*DIM;
            float e[DIM];
#pragma unroll
            for (int d = 0; d < DIM; ++d) e[d] = row[d];
            float A;
            ROWSQ(e, A);
            Cnp[i*KC + t] = A;
        }
    } else {
        // P[c] = gelu(E0[c]@W1+b1)@W2+b2  (exact erf gelu; tolerance loose)
        const int c = t;
        float e[DIM];
#pragma unroll
        for (int d = 0; d < DIM; ++d) e[d] = E[(size_t)c*DIM + d];
        float h[DIM];
        for (int m = 0; m < DIM; ++m) {
            float acc = b1[m];
            for (int d = 0; d < DIM; ++d) acc = fmaf(e[d], W1[d*DIM + m], acc);
            h[m] = 0.5f * acc * (1.0f + erff(acc * 0.70710678118654752440f));
        }
        for (int n = 0; n < DIM; ++n) {
            float acc = b2[n];
            for (int m = 0; m < DIM; ++m) acc = fmaf(h[m], W2[m*DIM + n], acc);
            P[c*DIM + n] = acc;
        }
    }
}

// =====================================================================
// scan of one staged 128-code half: acc[4][8] register tile, n-dim in
// 2 groups of 4 (e4[4] live) to fit the 64-VGPR (512,4) budget.
// ROUND-15 CHANGE: c-loop unrolled by 4 (c4 runtime, cc compile-time)
// so ds_read addresses fold into offset immediates (base + 16*cc) --
// kills ~16 address v_adds per c-iter + 4x loop control.  Unrolling a
// dependent-chain accumulator preserves the exact sequential c order
// -> bit-identical.  h==0 saves partial argmin; h==1 merges.
// =====================================================================
__device__ __forceinline__ void scan_half(
    const int h, const int i, const int j,
    const float* __restrict__ e_lds, const float* __restrict__ r_lds,
    const float* __restrict__ C_lds, const float* __restrict__ A_lds,
    float* __restrict__ bv1_lds, int* __restrict__ bk1_lds,
    int* __restrict__ bk_out) {
#pragma clang fp contract(off)
    float acc[4][8];
#pragma unroll
    for (int m = 0; m < 4; ++m)
#pragma unroll
        for (int n = 0; n < 8; ++n) acc[m][n] = 0.f;

#pragma unroll 1
    for (int c4 = 0; c4 < 16; c4 += 4) {
#pragma unroll
        for (int cc = 0; cc < 4; ++cc) {
            const int c = c4 + cc;
#pragma unroll
            for (int g = 0; g < 2; ++g) {
                float4 e4[4];
#pragma unroll
                for (int n = 0; n < 4; ++n)
                    e4[n] = *(const float4*)&e_lds[ESTRIDE*(j + 16*(4*g + n)) + 4*c];
#pragma unroll
                for (int m = 0; m < 4; ++m) {
                    float4 r4 = *(const float4*)&r_lds[(c*TOKB + (i + 32*m))*4];
#pragma unroll
                    for (int n = 0; n < 4; ++n) {
                        acc[m][4*g+n] = fmaf(r4.x, e4[n].x, acc[m][4*g+n]);
                        acc[m][4*g+n] = fmaf(r4.y, e4[n].y, acc[m][4*g+n]);
                        acc[m][4*g+n] = fmaf(r4.z, e4[n].z, acc[m][4*g+n]);
                        acc[m][4*g+n] = fmaf(r4.w, e4[n].w, acc[m][4*g+n]);
                    }
                }
            }
        }
    }

    float Ck[8];
#pragma unroll
    for (int n = 0; n < 8; ++n) Ck[n] = C_lds[j + 16*n];

#pragma unroll
    for (int m = 0; m < 4; ++m) {
        const float A = A_lds[i + 32*m];
        float bv = INFINITY; int bk = 0;
#pragma unroll
        for (int n = 0; n < 8; ++n) {
            const int k = h*HALF + j + 16*n;        // global code index
            const float x = fmaf(-2.0f, acc[m][n], A) + Ck[n];
            if (x < bv) { bv = x; bk = k; }          // first-min, k asc
        }
#pragma unroll
        for (int s = 8; s >= 1; s >>= 1) {
            const float ov = __shfl_xor(bv, s);
            const int   ok = __shfl_xor(bk, s);
            if (ov < bv || (ov == bv && ok < bk)) { bv = ov; bk = ok; }
        }
        if (j == 0) {
            if (h == 0) { bv1_lds[i + 32*m] = bv; bk1_lds[i + 32*m] = bk; }
            else {
                // every half-0 k < every half-1 k -> strict < keeps
                // np first-min semantics.
                const float v1 = bv1_lds[i + 32*m];
                const int   k1 = bk1_lds[i + 32*m];
                bk_out[i + 32*m] = (bv < v1) ? bk : k1;
            }
        }
    }
}

// =====================================================================
// Kernel M (FUSED): bit-exact np-f32 argmin chain + z_q_total +
// semantic partials.  512 threads = 32 token-groups x 16 code-groups,
// TOKB=128 tokens/block, codebook staged in TWO 128-code halves
// (LDS 72 KB -> 2 blocks/CU).  __launch_bounds__(512,4): proven 44%
// occupancy (round 11/14); (512,2) runs 1 block/CU (round 12).
// Epilogue replicates the old gather kernel bit-exactly.
// =====================================================================
__global__ __launch_bounds__(TPB, 4) void vq_main_kernel(
    const float* __restrict__ z, const float* __restrict__ Eg,
    const float* __restrict__ Cg, const float* __restrict__ P,
    const float* __restrict__ w2v,
    float* __restrict__ out_codes, float* __restrict__ out_codes0,
    float* __restrict__ out_zq,
    float* __restrict__ partial_vq, float* __restrict__ partial_sem) {
#pragma clang fp contract(off)
    __shared__ float e_lds[HALF*ESTRIDE];   // 34816 B
    __shared__ float r_lds[16*TOKB*4];      // 32768 B, float4 (chunk c, token)
    __shared__ float A_lds[TOKB];           // 512 B
    __shared__ float C_lds[HALF];           // 512 B
    __shared__ int   bkall_lds[NCB][TOKB];  // 2048 B (codes per cb)
    __shared__ float bv1_lds[TOKB];         // 512 B
    __shared__ int   bk1_lds[TOKB];         // 512 B
    __shared__ float red[TPB];              // 2048 B   => total 73728 B

    const int t = threadIdx.x;
    const int j = t & 15;                   // code group
    const int i = t >> 4;                   // token group (0..31)
    const int tokbase = blockIdx.x * TOKB;

    // ---- stage z -> r_lds (transposed: [c][token]) ----
    {
        const int tok = t >> 2;
        const int q0 = (t & 3) * 4;
        const float4* zp = (const float4*)(z + (size_t)(tokbase + tok)*DIM);
#pragma unroll
        for (int c = 0; c < 4; ++c) {
            float4 v = zp[q0 + c];
            *(float4*)&r_lds[((q0 + c)*TOKB + tok)*4] = v;
        }
    }
    __syncthreads();

    float vqacc = 0.f;

#pragma unroll 1
    for (int cb = 0; cb < NCB; ++cb) {
        // ---- A = ||r||^2 (np pairwise-8), current residual ----
        if (t < TOKB) {
            float rr[DIM];
#pragma unroll
            for (int c = 0; c < 16; ++c) {
                float4 v = *(const float4*)&r_lds[(c*TOKB + t)*4];
                rr[4*c+0]=v.x; rr[4*c+1]=v.y; rr[4*c+2]=v.z; rr[4*c+3]=v.w;
            }
            float A;
            ROWSQ(rr, A);
            A_lds[t] = A;
        }

        // ---- half 0: stage codes 0..127 + C, scan ----
        {
            const float* src = Eg + (size_t)cb*KC*DIM;
#pragma unroll
            for (int v = 0; v < 4; ++v) {
                const int idx = t*4 + v;               // 0..2047 float4s
                const int row = idx >> 4, ch = idx & 15;
                *(float4*)&e_lds[ESTRIDE*row + 4*ch] =
                    *(const float4*)(src + row*DIM + 4*ch);
            }
            if (t < HALF) C_lds[t] = Cg[cb*KC + t];
        }
        __syncthreads();
        scan_half(0, i, j, e_lds, r_lds, C_lds, A_lds, bv1_lds, bk1_lds,
                  &bkall_lds[cb][0]);
        __syncthreads();

        // ---- half 1: stage codes 128..255 + C, scan + merge ----
        {
            const float* src = Eg + ((size_t)cb*KC + HALF)*DIM;
#pragma unroll
            for (int v = 0; v < 4; ++v) {
                const int idx = t*4 + v;
                const int row = idx >> 4, ch = idx & 15;
                *(float4*)&e_lds[ESTRIDE*row + 4*ch] =
                    *(const float4*)(src + row*DIM + 4*ch);
            }
            if (t < HALF) C_lds[t] = Cg[cb*KC + HALF + t];
        }
        __syncthreads();
        scan_half(1, i, j, e_lds, r_lds, C_lds, A_lds, bv1_lds, bk1_lds,
                  &bkall_lds[cb][0]);
        __syncthreads();

        // ---- residual update (np-exact straight-through chain),
        //      winning e row from GLOBAL (L2-hot, identical bits) ----
        {
            const int tok = t >> 2;
            const int q0 = (t & 3) * 4;
            const int bk = bkall_lds[cb][tok];
            const float* ep = Eg + ((size_t)cb*KC + bk)*DIM;
#pragma unroll
            for (int c = 0; c < 4; ++c) {
                float* rp = &r_lds[((q0 + c)*TOKB + tok)*4];
                float4 rv = *(const float4*)rp;
                float4 ev = *(const float4*)(ep + 4*(q0 + c));
                float tt, st;
                tt = ev.x - rv.x; vqacc = fmaf(tt,tt,vqacc); st = rv.x + tt; rv.x = rv.x - st;
                tt = ev.y - rv.y; vqacc = fmaf(tt,tt,vqacc); st = rv.y + tt; rv.y = rv.y - st;
                tt = ev.z - rv.z; vqacc = fmaf(tt,tt,vqacc); st = rv.z + tt; rv.z = rv.z - st;
                tt = ev.w - rv.w; vqacc = fmaf(tt,tt,vqacc); st = rv.w + tt; rv.w = rv.w - st;
                *(float4*)rp = rv;
            }
        }
        __syncthreads();
    }

    // ================= fused epilogue (old gather kernel) =============
    float sem = 0.f;
    {
        const int tok = t >> 2;
        const int q0 = (t & 3) * 4;
        const int gtok = tokbase + tok;
        const int c0 = bkall_lds[0][tok], c1 = bkall_lds[1][tok];
        const int c2 = bkall_lds[2][tok], c3 = bkall_lds[3][tok];

        if ((t & 3) == 0) {
            *(float4*)(out_codes + (size_t)gtok*4) =
                make_float4((float)c0, (float)c1, (float)c2, (float)c3);
            out_codes0[gtok] = (float)c0;
        }

        const float4* zp = (const float4*)(z + (size_t)gtok*DIM);
        const float4* e0 = (const float4*)(Eg + (size_t)(0*KC + c0)*DIM);
        const float4* e1 = (const float4*)(Eg + (size_t)(1*KC + c1)*DIM);
        const float4* e2 = (const float4*)(Eg + (size_t)(2*KC + c2)*DIM);
        const float4* e3 = (const float4*)(Eg + (size_t)(3*KC + c3)*DIM);
        float4* o = (float4*)(out_zq + (size_t)gtok*DIM);
        const float4* pp = (const float4*)(P + (size_t)c0*DIM);
        const float4* wv = (const float4*)(w2v + (size_t)gtok*DIM);

#pragma unroll
        for (int q = q0; q < q0 + 4; ++q) {
            float4 zv = zp[q], a = e0[q], b = e1[q], c = e2[q], d = e3[q];
            float4 out;
            {
                float rr, tt, st, tot;
                rr = zv.x;
                tt = a.x - rr; st = rr + tt; tot = st;        rr = rr - st;
                tt = b.x - rr; st = rr + tt; tot = tot + st;  rr = rr - st;
                tt = c.x - rr; st = rr + tt; tot = tot + st;  rr = rr - st;
                tt = d.x - rr; st = rr + tt; tot = tot + st;
                out.x = tot;
            }
            {
                float rr, tt, st, tot;
                rr = zv.y;
                tt = a.y - rr; st = rr + tt; tot = st;        rr = rr - st;
                tt = b.y - rr; st = rr + tt; tot = tot + st;  rr = rr - st;
                tt = c.y - rr; st = rr + tt; tot = tot + st;  rr = rr - st;
                tt = d.y - rr; st = rr + tt; tot = tot + st;
                out.y = tot;
            }
            {
                float rr, tt, st, tot;
                rr = zv.z;
                tt = a.z - rr; st = rr + tt; tot = st;        rr = rr - st;
                tt = b.z - rr; st = rr + tt; tot = tot + st;  rr = rr - st;
                tt = c.z - rr; st = rr + tt; tot = tot + st;  rr = rr - st;
                tt = d.z - rr; st = rr + tt; tot = tot + st;
                out.z = tot;
            }
            {
                float rr, tt, st, tot;
                rr = zv.w;
                tt = a.w - rr; st = rr + tt; tot = st;        rr = rr - st;
                tt = b.w - rr; st = rr + tt; tot = tot + st;  rr = rr - st;
                tt = c.w - rr; st = rr + tt; tot = tot + st;  rr = rr - st;
                tt = d.w - rr; st = rr + tt; tot = tot + st;
                out.w = tot;
            }
            o[q] = out;

            float4 pv = pp[q], wvv = wv[q];
            float df;
            df = pv.x - wvv.x; sem = fmaf(df, df, sem);
            df = pv.y - wvv.y; sem = fmaf(df, df, sem);
            df = pv.z - wvv.z; sem = fmaf(df, df, sem);
            df = pv.w - wvv.w; sem = fmaf(df, df, sem);
        }
    }

    // deterministic block reductions: vq partial, then sem partial
    red[t] = vqacc;
    __syncthreads();
    for (int off = TPB/2; off > 0; off >>= 1) {
        if (t < off) red[t] += red[t + off];
        __syncthreads();
    }
    if (t == 0) partial_vq[blockIdx.x] = red[0];
    __syncthreads();
    red[t] = sem;
    __syncthreads();
    for (int off = TPB/2; off > 0; off >>= 1) {
        if (t < off) red[t] += red[t + off];
        __syncthreads();
    }
    if (t == 0) partial_sem[blockIdx.x] = red[0];
}

// =====================================================================
// Kernel R: deterministic final reduction -> loss scalars
// =====================================================================
__global__ __launch_bounds__(256) void reduce_kernel(
    const float* __restrict__ pvq, const float* __restrict__ psem,
    float* __restrict__ out_loss) {
    __shared__ float sv[256], ss[256];
    const int t = threadIdx.x;
    float a = 0.f, b = 0.f;
    for (int x = t; x < MGRID; x += 256) { a += pvq[x]; b += psem[x]; }
    sv[t] = a; ss[t] = b;
    __syncthreads();
    for (int off = 128; off > 0; off >>= 1) {
        if (t < off) { sv[t] += sv[t+off]; ss[t] += ss[t+off]; }
        __syncthreads();
    }
    if (t == 0) {
        // vq_loss = sum_i (1+0.25)*mean(t^2); semantic = mean((pred-w2v)^2)
        out_loss[0] = 1.25f * sv[0] / 16777216.0f;
        out_loss[1] = ss[0] / 16777216.0f;
    }
}

extern "C" void kernel_launch(void* const* d_in, const int* in_sizes, int n_in,
                              void* d_out, int out_size, void* d_ws, size_t ws_size,
                              hipStream_t stream) {
    (void)in_sizes; (void)n_in; (void)out_size; (void)ws_size;
    const float* z   = (const float*)d_in[0];
    const float* w2v = (const float*)d_in[1];
    const float* E   = (const float*)d_in[2];
    const float* W1  = (const float*)d_in[3];
    const float* b1  = (const float*)d_in[4];
    const float* W2  = (const float*)d_in[5];
    const float* b2  = (const float*)d_in[6];

    float* out = (float*)d_out;
    char*  ws  = (char*)d_ws;
    float* Cnp  = (float*)(ws + WS_C);
    float* P    = (float*)(ws + WS_P);
    float* pvq  = (float*)(ws + WS_PVQ);
    float* psem = (float*)(ws + WS_PSEM);

    float* out_zq     = out;                        // [B,T,64]
    float* out_codes  = out + 16777216;             // [B,T,4]
    float* out_codes0 = out + 17825792;             // [B,T]
    float* out_loss   = out + 18087936;             // vq_loss, semantic_loss

    precompute_kernel<<<2, 256, 0, stream>>>(E, W1, b1, W2, b2, Cnp, P);
    vq_main_kernel<<<MGRID, TPB, 0, stream>>>(z, E, Cnp, P, w2v,
                                              out_codes, out_codes0, out_zq,
                                              pvq, psem);
    reduce_kernel<<<1, 256, 0, stream>>>(pvq, psem, out_loss);
}

// Round 16
// 663.408 us; speedup vs baseline: 1.1684x; 1.1684x over previous
//
#include <hip/hip_runtime.h>
#include <math.h>

#define NCB 4
#define KC 256
#define DIM 64
#define NTOK (64*4096)            // 262144 tokens
#define TPB 512
#define TOKB 128                  // tokens per block
#define HALF 128                  // codes staged per half
#define MGRID (NTOK/TOKB)         // 2048 blocks

// ---- workspace byte offsets ----
#define WS_C     0            // 4*256*4   = 4096   (np-exact ||e||^2, f32)
#define WS_P     4096         // 256*64*4  = 65536  (semantic pred table)
#define WS_PVQ   69632        // 2048*4 = 8192
#define WS_PSEM  77824        // 2048*4 = 8192

#define ESTRIDE 68            // e_lds row stride in floats (bank decorrelation)

// np pairwise-8 sum of fl(r*r) (separate mul, NO fma)
#define ROWSQ(rr, A) { \
  float p0=rr[0]*rr[0], p1=rr[1]*rr[1], p2=rr[2]*rr[2], p3=rr[3]*rr[3]; \
  float p4=rr[4]*rr[4], p5=rr[5]*rr[5], p6=rr[6]*rr[6], p7=rr[7]*rr[7]; \
  _Pragma("unroll") \
  for (int m_ = 1; m_ < 8; ++m_) { \
    float s0=rr[8*m_+0]*rr[8*m_+0]; p0=p0+s0; float s1=rr[8*m_+1]*rr[8*m_+1]; p1=p1+s1; \
    float s2=rr[8*m_+2]*rr[8*m_+2]; p2=p2+s2; float s3=rr[8*m_+3]*rr[8*m_+3]; p3=p3+s3; \
    float s4=rr[8*m_+4]*rr[8*m_+4]; p4=p4+s4; float s5=rr[8*m_+5]*rr[8*m_+5]; p5=p5+s5; \
    float s6=rr[8*m_+6]*rr[8*m_+6]; p6=p6+s6; float s7=rr[8*m_+7]*rr[8*m_+7]; p7=p7+s7; \
  } \
  A = ((p0+p1) + (p2+p3)) + ((p4+p5) + (p6+p7)); }

// =====================================================================
// Kernel P: np-exact C tables (pairwise-8 sum of e^2) + semantic table
// =====================================================================
__global__ __launch_bounds__(256) void precompute_kernel(
    const float* __restrict__ E,
    const float* __restrict__ W1, const float* __restrict__ b1,
    const float* __restrict__ W2, const float* __restrict__ b2,
    float* __restrict__ Cnp, float* __restrict__ P) {
#pragma clang fp contract(off)
    const int t = threadIdx.x;
    if (blockIdx.x == 0) {
        for (int i = 0; i < NCB; ++i) {
            const float* row = E + (size_t)(i*KC + t)*DIM;
            float e[DIM];
#pragma unroll
            for (int d = 0; d < DIM; ++d) e[d] = row[d];
            float A;
            ROWSQ(e, A);
            Cnp[i*KC + t] = A;
        }
    } else {
        // P[c] = gelu(E0[c]@W1+b1)@W2+b2  (exact erf gelu; tolerance loose)
        const int c = t;
        float e[DIM];
#pragma unroll
        for (int d = 0; d < DIM; ++d) e[d] = E[(size_t)c*DIM + d];
        float h[DIM];
        for (int m = 0; m < DIM; ++m) {
            float acc = b1[m];
            for (int d = 0; d < DIM; ++d) acc = fmaf(e[d], W1[d*DIM + m], acc);
            h[m] = 0.5f * acc * (1.0f + erff(acc * 0.70710678118654752440f));
        }
        for (int n = 0; n < DIM; ++n) {
            float acc = b2[n];
            for (int m = 0; m < DIM; ++m) acc = fmaf(h[m], W2[m*DIM + n], acc);
            P[c*DIM + n] = acc;
        }
    }
}

// =====================================================================
// scan of one staged 128-code half.
// ROUND-16 RETILE: m=8 tokens x n=4 codes per thread (j = t&31 code
// group, i = t>>5 token group).  Per c-iter: 4 e-reads (stationary in
// regs across all 8 m) + 8 r-reads (2-distinct-addr broadcast) = 12
// ds_read_b128 vs round-14's 16 -- the LDS pipe is the measured
// bottleneck (1.57M cyc/CU ~= kernel duration).  Regs: acc 32 + e4 16
// + r4 4 + addr ~8 = ~60 <= the 64-VGPR (512,4) cap -> no spill.
// c-loop stays unroll-1 (round-15 lesson: unroll hoists loads -> huge
// scratch spill).  FMA chain per acc[m][n] keeps exact np sgemm order
// (c ascending, x/y/z/w) -> bit-identical.  In-thread k = j+32n
// ascending; 32-lane lexicographic shfl merge; h==0 saves, h==1 merges
// (all half-0 k < all half-1 k -> strict < keeps np first-min).
// =====================================================================
__device__ __forceinline__ void scan_half(
    const int h, const int i, const int j,
    const float* __restrict__ e_lds, const float* __restrict__ r_lds,
    const float* __restrict__ C_lds, const float* __restrict__ A_lds,
    float* __restrict__ bv1_lds, int* __restrict__ bk1_lds,
    int* __restrict__ bk_out) {
#pragma clang fp contract(off)
    float acc[8][4];
#pragma unroll
    for (int m = 0; m < 8; ++m)
#pragma unroll
        for (int n = 0; n < 4; ++n) acc[m][n] = 0.f;

#pragma unroll 1
    for (int c = 0; c < 16; ++c) {
        float4 e4[4];
#pragma unroll
        for (int n = 0; n < 4; ++n)
            e4[n] = *(const float4*)&e_lds[ESTRIDE*(j + 32*n) + 4*c];
#pragma unroll
        for (int m = 0; m < 8; ++m) {
            float4 r4 = *(const float4*)&r_lds[(c*TOKB + (i + 16*m))*4];
#pragma unroll
            for (int n = 0; n < 4; ++n) {
                acc[m][n] = fmaf(r4.x, e4[n].x, acc[m][n]);
                acc[m][n] = fmaf(r4.y, e4[n].y, acc[m][n]);
                acc[m][n] = fmaf(r4.z, e4[n].z, acc[m][n]);
                acc[m][n] = fmaf(r4.w, e4[n].w, acc[m][n]);
            }
        }
    }

    float Ck[4];
#pragma unroll
    for (int n = 0; n < 4; ++n) Ck[n] = C_lds[j + 32*n];

#pragma unroll
    for (int m = 0; m < 8; ++m) {
        const float A = A_lds[i + 16*m];
        float bv = INFINITY; int bk = 0;
#pragma unroll
        for (int n = 0; n < 4; ++n) {
            const int k = h*HALF + j + 32*n;        // global code index
            const float x = fmaf(-2.0f, acc[m][n], A) + Ck[n];
            if (x < bv) { bv = x; bk = k; }          // first-min, k asc
        }
#pragma unroll
        for (int s = 16; s >= 1; s >>= 1) {
            const float ov = __shfl_xor(bv, s);
            const int   ok = __shfl_xor(bk, s);
            if (ov < bv || (ov == bv && ok < bk)) { bv = ov; bk = ok; }
        }
        if (j == 0) {
            if (h == 0) { bv1_lds[i + 16*m] = bv; bk1_lds[i + 16*m] = bk; }
            else {
                const float v1 = bv1_lds[i + 16*m];
                const int   k1 = bk1_lds[i + 16*m];
                bk_out[i + 16*m] = (bv < v1) ? bk : k1;
            }
        }
    }
}

// =====================================================================
// Kernel M (FUSED): bit-exact np-f32 argmin chain + z_q_total +
// semantic partials.  512 threads, TOKB=128 tokens/block, codebook
// staged in TWO 128-code halves (LDS 72 KB -> 2 blocks/CU).
// __launch_bounds__(512,4): proven 44% occupancy (rounds 11/14).
// Epilogue replicates the old gather kernel bit-exactly.
// =====================================================================
__global__ __launch_bounds__(TPB, 4) void vq_main_kernel(
    const float* __restrict__ z, const float* __restrict__ Eg,
    const float* __restrict__ Cg, const float* __restrict__ P,
    const float* __restrict__ w2v,
    float* __restrict__ out_codes, float* __restrict__ out_codes0,
    float* __restrict__ out_zq,
    float* __restrict__ partial_vq, float* __restrict__ partial_sem) {
#pragma clang fp contract(off)
    __shared__ float e_lds[HALF*ESTRIDE];   // 34816 B
    __shared__ float r_lds[16*TOKB*4];      // 32768 B, float4 (chunk c, token)
    __shared__ float A_lds[TOKB];           // 512 B
    __shared__ float C_lds[HALF];           // 512 B
    __shared__ int   bkall_lds[NCB][TOKB];  // 2048 B (codes per cb)
    __shared__ float bv1_lds[TOKB];         // 512 B
    __shared__ int   bk1_lds[TOKB];         // 512 B
    __shared__ float red[TPB];              // 2048 B   => total 73728 B

    const int t = threadIdx.x;
    const int j = t & 31;                   // code group (32-wide)
    const int i = t >> 5;                   // token group (0..15)
    const int tokbase = blockIdx.x * TOKB;

    // ---- stage z -> r_lds (transposed: [c][token]) ----
    {
        const int tok = t >> 2;
        const int q0 = (t & 3) * 4;
        const float4* zp = (const float4*)(z + (size_t)(tokbase + tok)*DIM);
#pragma unroll
        for (int c = 0; c < 4; ++c) {
            float4 v = zp[q0 + c];
            *(float4*)&r_lds[((q0 + c)*TOKB + tok)*4] = v;
        }
    }
    __syncthreads();

    float vqacc = 0.f;

#pragma unroll 1
    for (int cb = 0; cb < NCB; ++cb) {
        // ---- A = ||r||^2 (np pairwise-8), current residual ----
        if (t < TOKB) {
            float rr[DIM];
#pragma unroll
            for (int c = 0; c < 16; ++c) {
                float4 v = *(const float4*)&r_lds[(c*TOKB + t)*4];
                rr[4*c+0]=v.x; rr[4*c+1]=v.y; rr[4*c+2]=v.z; rr[4*c+3]=v.w;
            }
            float A;
            ROWSQ(rr, A);
            A_lds[t] = A;
        }

        // ---- half 0: stage codes 0..127 + C, scan ----
        {
            const float* src = Eg + (size_t)cb*KC*DIM;
#pragma unroll
            for (int v = 0; v < 4; ++v) {
                const int idx = t*4 + v;               // 0..2047 float4s
                const int row = idx >> 4, ch = idx & 15;
                *(float4*)&e_lds[ESTRIDE*row + 4*ch] =
                    *(const float4*)(src + row*DIM + 4*ch);
            }
            if (t < HALF) C_lds[t] = Cg[cb*KC + t];
        }
        __syncthreads();
        scan_half(0, i, j, e_lds, r_lds, C_lds, A_lds, bv1_lds, bk1_lds,
                  &bkall_lds[cb][0]);
        __syncthreads();

        // ---- half 1: stage codes 128..255 + C, scan + merge ----
        {
            const float* src = Eg + ((size_t)cb*KC + HALF)*DIM;
#pragma unroll
            for (int v = 0; v < 4; ++v) {
                const int idx = t*4 + v;
                const int row = idx >> 4, ch = idx & 15;
                *(float4*)&e_lds[ESTRIDE*row + 4*ch] =
                    *(const float4*)(src + row*DIM + 4*ch);
            }
            if (t < HALF) C_lds[t] = Cg[cb*KC + HALF + t];
        }
        __syncthreads();
        scan_half(1, i, j, e_lds, r_lds, C_lds, A_lds, bv1_lds, bk1_lds,
                  &bkall_lds[cb][0]);
        __syncthreads();

        // ---- residual update (np-exact straight-through chain),
        //      winning e row from GLOBAL (L2-hot, identical bits) ----
        {
            const int tok = t >> 2;
            const int q0 = (t & 3) * 4;
            const int bk = bkall_lds[cb][tok];
            const float* ep = Eg + ((size_t)cb*KC + bk)*DIM;
#pragma unroll
            for (int c = 0; c < 4; ++c) {
                float* rp = &r_lds[((q0 + c)*TOKB + tok)*4];
                float4 rv = *(const float4*)rp;
                float4 ev = *(const float4*)(ep + 4*(q0 + c));
                float tt, st;
                tt = ev.x - rv.x; vqacc = fmaf(tt,tt,vqacc); st = rv.x + tt; rv.x = rv.x - st;
                tt = ev.y - rv.y; vqacc = fmaf(tt,tt,vqacc); st = rv.y + tt; rv.y = rv.y - st;
                tt = ev.z - rv.z; vqacc = fmaf(tt,tt,vqacc); st = rv.z + tt; rv.z = rv.z - st;
                tt = ev.w - rv.w; vqacc = fmaf(tt,tt,vqacc); st = rv.w + tt; rv.w = rv.w - st;
                *(float4*)rp = rv;
            }
        }
        __syncthreads();
    }

    // ================= fused epilogue (old gather kernel) =============
    float sem = 0.f;
    {
        const int tok = t >> 2;
        const int q0 = (t & 3) * 4;
        const int gtok = tokbase + tok;
        const int c0 = bkall_lds[0][tok], c1 = bkall_lds[1][tok];
        const int c2 = bkall_lds[2][tok], c3 = bkall_lds[3][tok];

        if ((t & 3) == 0) {
            *(float4*)(out_codes + (size_t)gtok*4) =
                make_float4((float)c0, (float)c1, (float)c2, (float)c3);
            out_codes0[gtok] = (float)c0;
        }

        const float4* zp = (const float4*)(z + (size_t)gtok*DIM);
        const float4* e0 = (const float4*)(Eg + (size_t)(0*KC + c0)*DIM);
        const float4* e1 = (const float4*)(Eg + (size_t)(1*KC + c1)*DIM);
        const float4* e2 = (const float4*)(Eg + (size_t)(2*KC + c2)*DIM);
        const float4* e3 = (const float4*)(Eg + (size_t)(3*KC + c3)*DIM);
        float4* o = (float4*)(out_zq + (size_t)gtok*DIM);
        const float4* pp = (const float4*)(P + (size_t)c0*DIM);
        const float4* wv = (const float4*)(w2v + (size_t)gtok*DIM);

#pragma unroll
        for (int q = q0; q < q0 + 4; ++q) {
            float4 zv = zp[q], a = e0[q], b = e1[q], c = e2[q], d = e3[q];
            float4 out;
            {
                float rr, tt, st, tot;
                rr = zv.x;
                tt = a.x - rr; st = rr + tt; tot = st;        rr = rr - st;
                tt = b.x - rr; st = rr + tt; tot = tot + st;  rr = rr - st;
                tt = c.x - rr; st = rr + tt; tot = tot + st;  rr = rr - st;
                tt = d.x - rr; st = rr + tt; tot = tot + st;
                out.x = tot;
            }
            {
                float rr, tt, st, tot;
                rr = zv.y;
                tt = a.y - rr; st = rr + tt; tot = st;        rr = rr - st;
                tt = b.y - rr; st = rr + tt; tot = tot + st;  rr = rr - st;
                tt = c.y - rr; st = rr + tt; tot = tot + st;  rr = rr - st;
                tt = d.y - rr; st = rr + tt; tot = tot + st;
                out.y = tot;
            }
            {
                float rr, tt, st, tot;
                rr = zv.z;
                tt = a.z - rr; st = rr + tt; tot = st;        rr = rr - st;
                tt = b.z - rr; st = rr + tt; tot = tot + st;  rr = rr - st;
                tt = c.z - rr; st = rr + tt; tot = tot + st;  rr = rr - st;
                tt = d.z - rr; st = rr + tt; tot = tot + st;
                out.z = tot;
            }
            {
                float rr, tt, st, tot;
                rr = zv.w;
                tt = a.w - rr; st = rr + tt; tot = st;        rr = rr - st;
                tt = b.w - rr; st = rr + tt; tot = tot + st;  rr = rr - st;
                tt = c.w - rr; st = rr + tt; tot = tot + st;  rr = rr - st;
                tt = d.w - rr; st = rr + tt; tot = tot + st;
                out.w = tot;
            }
            o[q] = out;

            float4 pv = pp[q], wvv = wv[q];
            float df;
            df = pv.x - wvv.x; sem = fmaf(df, df, sem);
            df = pv.y - wvv.y; sem = fmaf(df, df, sem);
            df = pv.z - wvv.z; sem = fmaf(df, df, sem);
            df = pv.w - wvv.w; sem = fmaf(df, df, sem);
        }
    }

    // deterministic block reductions: vq partial, then sem partial
    red[t] = vqacc;
    __syncthreads();
    for (int off = TPB/2; off > 0; off >>= 1) {
        if (t < off) red[t] += red[t + off];
        __syncthreads();
    }
    if (t == 0) partial_vq[blockIdx.x] = red[0];
    __syncthreads();
    red[t] = sem;
    __syncthreads();
    for (int off = TPB/2; off > 0; off >>= 1) {
        if (t < off) red[t] += red[t + off];
        __syncthreads();
    }
    if (t == 0) partial_sem[blockIdx.x] = red[0];
}

// =====================================================================
// Kernel R: deterministic final reduction -> loss scalars
// =====================================================================
__global__ __launch_bounds__(256) void reduce_kernel(
    const float* __restrict__ pvq, const float* __restrict__ psem,
    float* __restrict__ out_loss) {
    __shared__ float sv[256], ss[256];
    const int t = threadIdx.x;
    float a = 0.f, b = 0.f;
    for (int x = t; x < MGRID; x += 256) { a += pvq[x]; b += psem[x]; }
    sv[t] = a; ss[t] = b;
    __syncthreads();
    for (int off = 128; off > 0; off >>= 1) {
        if (t < off) { sv[t] += sv[t+off]; ss[t] += ss[t+off]; }
        __syncthreads();
    }
    if (t == 0) {
        // vq_loss = sum_i (1+0.25)*mean(t^2); semantic = mean((pred-w2v)^2)
        out_loss[0] = 1.25f * sv[0] / 16777216.0f;
        out_loss[1] = ss[0] / 16777216.0f;
    }
}

extern "C" void kernel_launch(void* const* d_in, const int* in_sizes, int n_in,
                              void* d_out, int out_size, void* d_ws, size_t ws_size,
                              hipStream_t stream) {
    (void)in_sizes; (void)n_in; (void)out_size; (void)ws_size;
    const float* z   = (const float*)d_in[0];
    const float* w2v = (const float*)d_in[1];
    const float* E   = (const float*)d_in[2];
    const float* W1  = (const float*)d_in[3];
    const float* b1  = (const float*)d_in[4];
    const float* W2  = (const float*)d_in[5];
    const float* b2  = (const float*)d_in[6];

    float* out = (float*)d_out;
    char*  ws  = (char*)d_ws;
    float* Cnp  = (float*)(ws + WS_C);
    float* P    = (float*)(ws + WS_P);
    float* pvq  = (float*)(ws + WS_PVQ);
    float* psem = (float*)(ws + WS_PSEM);

    float* out_zq     = out;                        // [B,T,64]
    float* out_codes  = out + 16777216;             // [B,T,4]
    float* out_codes0 = out + 17825792;             // [B,T]
    float* out_loss   = out + 18087936;             // vq_loss, semantic_loss

    precompute_kernel<<<2, 256, 0, stream>>>(E, W1, b1, W2, b2, Cnp, P);
    vq_main_kernel<<<MGRID, TPB, 0, stream>>>(z, E, Cnp, P, w2v,
                                              out_codes, out_codes0, out_zq,
                                              pvq, psem);
    reduce_kernel<<<1, 256, 0, stream>>>(pvq, psem, out_loss);
}

// Round 17
// 597.125 us; speedup vs baseline: 1.2981x; 1.1110x over previous
//
#include <hip/hip_runtime.h>
#include <math.h>

#define NCB 4
#define KC 256
#define DIM 64
#define NTOK (64*4096)            // 262144 tokens
#define TPB 512
#define TOKB 128                  // tokens per block
#define HALF 128                  // codes staged per half
#define MGRID (NTOK/TOKB)         // 2048 blocks

// ---- workspace byte offsets ----
#define WS_C     0            // 4*256*4   = 4096   (np-exact ||e||^2, f32)
#define WS_P     4096         // 256*64*4  = 65536  (semantic pred table)
#define WS_PVQ   69632        // 2048*4 = 8192
#define WS_PSEM  77824        // 2048*4 = 8192

#define ESTRIDE 68            // e_lds row stride in floats (bank decorrelation)

// np pairwise-8 sum of fl(r*r) (separate mul, NO fma)
#define ROWSQ(rr, A) { \
  float p0=rr[0]*rr[0], p1=rr[1]*rr[1], p2=rr[2]*rr[2], p3=rr[3]*rr[3]; \
  float p4=rr[4]*rr[4], p5=rr[5]*rr[5], p6=rr[6]*rr[6], p7=rr[7]*rr[7]; \
  _Pragma("unroll") \
  for (int m_ = 1; m_ < 8; ++m_) { \
    float s0=rr[8*m_+0]*rr[8*m_+0]; p0=p0+s0; float s1=rr[8*m_+1]*rr[8*m_+1]; p1=p1+s1; \
    float s2=rr[8*m_+2]*rr[8*m_+2]; p2=p2+s2; float s3=rr[8*m_+3]*rr[8*m_+3]; p3=p3+s3; \
    float s4=rr[8*m_+4]*rr[8*m_+4]; p4=p4+s4; float s5=rr[8*m_+5]*rr[8*m_+5]; p5=p5+s5; \
    float s6=rr[8*m_+6]*rr[8*m_+6]; p6=p6+s6; float s7=rr[8*m_+7]*rr[8*m_+7]; p7=p7+s7; \
  } \
  A = ((p0+p1) + (p2+p3)) + ((p4+p5) + (p6+p7)); }

// =====================================================================
// Kernel P: np-exact C tables (pairwise-8 sum of e^2) + semantic table
// =====================================================================
__global__ __launch_bounds__(256) void precompute_kernel(
    const float* __restrict__ E,
    const float* __restrict__ W1, const float* __restrict__ b1,
    const float* __restrict__ W2, const float* __restrict__ b2,
    float* __restrict__ Cnp, float* __restrict__ P) {
#pragma clang fp contract(off)
    const int t = threadIdx.x;
    if (blockIdx.x == 0) {
        for (int i = 0; i < NCB; ++i) {
            const float* row = E + (size_t)(i*KC + t)*DIM;
            float e[DIM];
#pragma unroll
            for (int d = 0; d < DIM; ++d) e[d] = row[d];
            float A;
            ROWSQ(e, A);
            Cnp[i*KC + t] = A;
        }
    } else {
        // P[c] = gelu(E0[c]@W1+b1)@W2+b2  (exact erf gelu; tolerance loose)
        const int c = t;
        float e[DIM];
#pragma unroll
        for (int d = 0; d < DIM; ++d) e[d] = E[(size_t)c*DIM + d];
        float h[DIM];
        for (int m = 0; m < DIM; ++m) {
            float acc = b1[m];
            for (int d = 0; d < DIM; ++d) acc = fmaf(e[d], W1[d*DIM + m], acc);
            h[m] = 0.5f * acc * (1.0f + erff(acc * 0.70710678118654752440f));
        }
        for (int n = 0; n < DIM; ++n) {
            float acc = b2[n];
            for (int m = 0; m < DIM; ++m) acc = fmaf(h[m], W2[m*DIM + n], acc);
            P[c*DIM + n] = acc;
        }
    }
}

// =====================================================================
// scan of one staged 128-code half: acc[4][8] register tile with
// e4[8] held live across all 4 m (12 ds_read/c-iter vs 16) -- the
// round-11 proven-bit-exact body.  Fits the 128-VGPR budget granted
// by amdgpu_waves_per_eu(4,4) (round-17 change); at the old 64-reg
// (512,4) budget this spilled (round 11).  c-loop unroll-1 (round-15
// lesson).  FMA chain per acc[m][n]: exact np sgemm order.
// h==0 saves partial argmin; h==1 merges (all half-0 k < half-1 k).
// =====================================================================
__device__ __forceinline__ void scan_half(
    const int h, const int i, const int j,
    const float* __restrict__ e_lds, const float* __restrict__ r_lds,
    const float* __restrict__ C_lds, const float* __restrict__ A_lds,
    float* __restrict__ bv1_lds, int* __restrict__ bk1_lds,
    int* __restrict__ bk_out) {
#pragma clang fp contract(off)
    float acc[4][8];
#pragma unroll
    for (int m = 0; m < 4; ++m)
#pragma unroll
        for (int n = 0; n < 8; ++n) acc[m][n] = 0.f;

#pragma unroll 1
    for (int c = 0; c < 16; ++c) {
        float4 e4[8];
#pragma unroll
        for (int n = 0; n < 8; ++n)
            e4[n] = *(const float4*)&e_lds[ESTRIDE*(j + 16*n) + 4*c];
#pragma unroll
        for (int m = 0; m < 4; ++m) {
            float4 r4 = *(const float4*)&r_lds[(c*TOKB + (i + 32*m))*4];
#pragma unroll
            for (int n = 0; n < 8; ++n) {
                // sequential np sgemm chain: d ascending, x,y,z,w order
                acc[m][n] = fmaf(r4.x, e4[n].x, acc[m][n]);
                acc[m][n] = fmaf(r4.y, e4[n].y, acc[m][n]);
                acc[m][n] = fmaf(r4.z, e4[n].z, acc[m][n]);
                acc[m][n] = fmaf(r4.w, e4[n].w, acc[m][n]);
            }
        }
    }

    float Ck[8];
#pragma unroll
    for (int n = 0; n < 8; ++n) Ck[n] = C_lds[j + 16*n];

#pragma unroll
    for (int m = 0; m < 4; ++m) {
        const float A = A_lds[i + 32*m];
        float bv = INFINITY; int bk = 0;
#pragma unroll
        for (int n = 0; n < 8; ++n) {
            const int k = h*HALF + j + 16*n;        // global code index
            const float x = fmaf(-2.0f, acc[m][n], A) + Ck[n];
            if (x < bv) { bv = x; bk = k; }          // first-min, k asc
        }
#pragma unroll
        for (int s = 8; s >= 1; s >>= 1) {
            const float ov = __shfl_xor(bv, s);
            const int   ok = __shfl_xor(bk, s);
            if (ov < bv || (ov == bv && ok < bk)) { bv = ov; bk = ok; }
        }
        if (j == 0) {
            if (h == 0) { bv1_lds[i + 32*m] = bv; bk1_lds[i + 32*m] = bk; }
            else {
                // every half-0 k < every half-1 k -> strict < keeps
                // np first-min semantics.
                const float v1 = bv1_lds[i + 32*m];
                const int   k1 = bk1_lds[i + 32*m];
                bk_out[i + 32*m] = (bv < v1) ? bk : k1;
            }
        }
    }
}

// =====================================================================
// Kernel M (FUSED): bit-exact np-f32 argmin chain + z_q_total +
// semantic partials.  512 threads = 32 token-groups x 16 code-groups,
// TOKB=128, codebook staged in TWO 128-code halves (LDS 72 KB ->
// 2 blocks/CU).  ROUND-17: amdgpu_waves_per_eu(4,4) replaces the
// (512,4) 2nd arg -- budgets 512/4 = 128 VGPRs while capping at
// 16 waves/CU (= exactly our 2 LDS-limited blocks), vs (512,4)'s
// empirical 64-reg budget (rounds 11/14/16) and (512,2)'s 8-wave
// occupancy (round 12).  Lets the 12-read/c e4[8] scan live spill-free.
// =====================================================================
__global__ __launch_bounds__(TPB)
__attribute__((amdgpu_waves_per_eu(4, 4)))
void vq_main_kernel(
    const float* __restrict__ z, const float* __restrict__ Eg,
    const float* __restrict__ Cg, const float* __restrict__ P,
    const float* __restrict__ w2v,
    float* __restrict__ out_codes, float* __restrict__ out_codes0,
    float* __restrict__ out_zq,
    float* __restrict__ partial_vq, float* __restrict__ partial_sem) {
#pragma clang fp contract(off)
    __shared__ float e_lds[HALF*ESTRIDE];   // 34816 B
    __shared__ float r_lds[16*TOKB*4];      // 32768 B, float4 (chunk c, token)
    __shared__ float A_lds[TOKB];           // 512 B
    __shared__ float C_lds[HALF];           // 512 B
    __shared__ int   bkall_lds[NCB][TOKB];  // 2048 B (codes per cb)
    __shared__ float bv1_lds[TOKB];         // 512 B
    __shared__ int   bk1_lds[TOKB];         // 512 B
    __shared__ float red[TPB];              // 2048 B   => total 73728 B

    const int t = threadIdx.x;
    const int j = t & 15;                   // code group
    const int i = t >> 4;                   // token group (0..31)
    const int tokbase = blockIdx.x * TOKB;

    // ---- stage z -> r_lds (transposed: [c][token]) ----
    {
        const int tok = t >> 2;
        const int q0 = (t & 3) * 4;
        const float4* zp = (const float4*)(z + (size_t)(tokbase + tok)*DIM);
#pragma unroll
        for (int c = 0; c < 4; ++c) {
            float4 v = zp[q0 + c];
            *(float4*)&r_lds[((q0 + c)*TOKB + tok)*4] = v;
        }
    }
    __syncthreads();

    float vqacc = 0.f;

#pragma unroll 1
    for (int cb = 0; cb < NCB; ++cb) {
        // ---- A = ||r||^2 (np pairwise-8), current residual ----
        if (t < TOKB) {
            float rr[DIM];
#pragma unroll
            for (int c = 0; c < 16; ++c) {
                float4 v = *(const float4*)&r_lds[(c*TOKB + t)*4];
                rr[4*c+0]=v.x; rr[4*c+1]=v.y; rr[4*c+2]=v.z; rr[4*c+3]=v.w;
            }
            float A;
            ROWSQ(rr, A);
            A_lds[t] = A;
        }

        // ---- half 0: stage codes 0..127 + C, scan ----
        {
            const float* src = Eg + (size_t)cb*KC*DIM;
#pragma unroll
            for (int v = 0; v < 4; ++v) {
                const int idx = t*4 + v;               // 0..2047 float4s
                const int row = idx >> 4, ch = idx & 15;
                *(float4*)&e_lds[ESTRIDE*row + 4*ch] =
                    *(const float4*)(src + row*DIM + 4*ch);
            }
            if (t < HALF) C_lds[t] = Cg[cb*KC + t];
        }
        __syncthreads();
        scan_half(0, i, j, e_lds, r_lds, C_lds, A_lds, bv1_lds, bk1_lds,
                  &bkall_lds[cb][0]);
        __syncthreads();

        // ---- half 1: stage codes 128..255 + C, scan + merge ----
        {
            const float* src = Eg + ((size_t)cb*KC + HALF)*DIM;
#pragma unroll
            for (int v = 0; v < 4; ++v) {
                const int idx = t*4 + v;
                const int row = idx >> 4, ch = idx & 15;
                *(float4*)&e_lds[ESTRIDE*row + 4*ch] =
                    *(const float4*)(src + row*DIM + 4*ch);
            }
            if (t < HALF) C_lds[t] = Cg[cb*KC + HALF + t];
        }
        __syncthreads();
        scan_half(1, i, j, e_lds, r_lds, C_lds, A_lds, bv1_lds, bk1_lds,
                  &bkall_lds[cb][0]);
        __syncthreads();

        // ---- residual update (np-exact straight-through chain),
        //      winning e row from GLOBAL (L2-hot, identical bits) ----
        {
            const int tok = t >> 2;
            const int q0 = (t & 3) * 4;
            const int bk = bkall_lds[cb][tok];
            const float* ep = Eg + ((size_t)cb*KC + bk)*DIM;
#pragma unroll
            for (int c = 0; c < 4; ++c) {
                float* rp = &r_lds[((q0 + c)*TOKB + tok)*4];
                float4 rv = *(const float4*)rp;
                float4 ev = *(const float4*)(ep + 4*(q0 + c));
                float tt, st;
                tt = ev.x - rv.x; vqacc = fmaf(tt,tt,vqacc); st = rv.x + tt; rv.x = rv.x - st;
                tt = ev.y - rv.y; vqacc = fmaf(tt,tt,vqacc); st = rv.y + tt; rv.y = rv.y - st;
                tt = ev.z - rv.z; vqacc = fmaf(tt,tt,vqacc); st = rv.z + tt; rv.z = rv.z - st;
                tt = ev.w - rv.w; vqacc = fmaf(tt,tt,vqacc); st = rv.w + tt; rv.w = rv.w - st;
                *(float4*)rp = rv;
            }
        }
        __syncthreads();
    }

    // ================= fused epilogue (old gather kernel) =============
    float sem = 0.f;
    {
        const int tok = t >> 2;
        const int q0 = (t & 3) * 4;
        const int gtok = tokbase + tok;
        const int c0 = bkall_lds[0][tok], c1 = bkall_lds[1][tok];
        const int c2 = bkall_lds[2][tok], c3 = bkall_lds[3][tok];

        if ((t & 3) == 0) {
            *(float4*)(out_codes + (size_t)gtok*4) =
                make_float4((float)c0, (float)c1, (float)c2, (float)c3);
            out_codes0[gtok] = (float)c0;
        }

        const float4* zp = (const float4*)(z + (size_t)gtok*DIM);
        const float4* e0 = (const float4*)(Eg + (size_t)(0*KC + c0)*DIM);
        const float4* e1 = (const float4*)(Eg + (size_t)(1*KC + c1)*DIM);
        const float4* e2 = (const float4*)(Eg + (size_t)(2*KC + c2)*DIM);
        const float4* e3 = (const float4*)(Eg + (size_t)(3*KC + c3)*DIM);
        float4* o = (float4*)(out_zq + (size_t)gtok*DIM);
        const float4* pp = (const float4*)(P + (size_t)c0*DIM);
        const float4* wv = (const float4*)(w2v + (size_t)gtok*DIM);

#pragma unroll
        for (int q = q0; q < q0 + 4; ++q) {
            float4 zv = zp[q], a = e0[q], b = e1[q], c = e2[q], d = e3[q];
            float4 out;
            {
                float rr, tt, st, tot;
                rr = zv.x;
                tt = a.x - rr; st = rr + tt; tot = st;        rr = rr - st;
                tt = b.x - rr; st = rr + tt; tot = tot + st;  rr = rr - st;
                tt = c.x - rr; st = rr + tt; tot = tot + st;  rr = rr - st;
                tt = d.x - rr; st = rr + tt; tot = tot + st;
                out.x = tot;
            }
            {
                float rr, tt, st, tot;
                rr = zv.y;
                tt = a.y - rr; st = rr + tt; tot = st;        rr = rr - st;
                tt = b.y - rr; st = rr + tt; tot = tot + st;  rr = rr - st;
                tt = c.y - rr; st = rr + tt; tot = tot + st;  rr = rr - st;
                tt = d.y - rr; st = rr + tt; tot = tot + st;
                out.y = tot;
            }
            {
                float rr, tt, st, tot;
                rr = zv.z;
                tt = a.z - rr; st = rr + tt; tot = st;        rr = rr - st;
                tt = b.z - rr; st = rr + tt; tot = tot + st;  rr = rr - st;
                tt = c.z - rr; st = rr + tt; tot = tot + st;  rr = rr - st;
                tt = d.z - rr; st = rr + tt; tot = tot + st;
                out.z = tot;
            }
            {
                float rr, tt, st, tot;
                rr = zv.w;
                tt = a.w - rr; st = rr + tt; tot = st;        rr = rr - st;
                tt = b.w - rr; st = rr + tt; tot = tot + st;  rr = rr - st;
                tt = c.w - rr; st = rr + tt; tot = tot + st;  rr = rr - st;
                tt = d.w - rr; st = rr + tt; tot = tot + st;
                out.w = tot;
            }
            o[q] = out;

            float4 pv = pp[q], wvv = wv[q];
            float df;
            df = pv.x - wvv.x; sem = fmaf(df, df, sem);
            df = pv.y - wvv.y; sem = fmaf(df, df, sem);
            df = pv.z - wvv.z; sem = fmaf(df, df, sem);
            df = pv.w - wvv.w; sem = fmaf(df, df, sem);
        }
    }

    // deterministic block reductions: vq partial, then sem partial
    red[t] = vqacc;
    __syncthreads();
    for (int off = TPB/2; off > 0; off >>= 1) {
        if (t < off) red[t] += red[t + off];
        __syncthreads();
    }
    if (t == 0) partial_vq[blockIdx.x] = red[0];
    __syncthreads();
    red[t] = sem;
    __syncthreads();
    for (int off = TPB/2; off > 0; off >>= 1) {
        if (t < off) red[t] += red[t + off];
        __syncthreads();
    }
    if (t == 0) partial_sem[blockIdx.x] = red[0];
}

// =====================================================================
// Kernel R: deterministic final reduction -> loss scalars
// =====================================================================
__global__ __launch_bounds__(256) void reduce_kernel(
    const float* __restrict__ pvq, const float* __restrict__ psem,
    float* __restrict__ out_loss) {
    __shared__ float sv[256], ss[256];
    const int t = threadIdx.x;
    float a = 0.f, b = 0.f;
    for (int x = t; x < MGRID; x += 256) { a += pvq[x]; b += psem[x]; }
    sv[t] = a; ss[t] = b;
    __syncthreads();
    for (int off = 128; off > 0; off >>= 1) {
        if (t < off) { sv[t] += sv[t+off]; ss[t] += ss[t+off]; }
        __syncthreads();
    }
    if (t == 0) {
        // vq_loss = sum_i (1+0.25)*mean(t^2); semantic = mean((pred-w2v)^2)
        out_loss[0] = 1.25f * sv[0] / 16777216.0f;
        out_loss[1] = ss[0] / 16777216.0f;
    }
}

extern "C" void kernel_launch(void* const* d_in, const int* in_sizes, int n_in,
                              void* d_out, int out_size, void* d_ws, size_t ws_size,
                              hipStream_t stream) {
    (void)in_sizes; (void)n_in; (void)out_size; (void)ws_size;
    const float* z   = (const float*)d_in[0];
    const float* w2v = (const float*)d_in[1];
    const float* E   = (const float*)d_in[2];
    const float* W1  = (const float*)d_in[3];
    const float* b1  = (const float*)d_in[4];
    const float* W2  = (const float*)d_in[5];
    const float* b2  = (const float*)d_in[6];

    float* out = (float*)d_out;
    char*  ws  = (char*)d_ws;
    float* Cnp  = (float*)(ws + WS_C);
    float* P    = (float*)(ws + WS_P);
    float* pvq  = (float*)(ws + WS_PVQ);
    float* psem = (float*)(ws + WS_PSEM);

    float* out_zq     = out;                        // [B,T,64]
    float* out_codes  = out + 16777216;             // [B,T,4]
    float* out_codes0 = out + 17825792;             // [B,T]
    float* out_loss   = out + 18087936;             // vq_loss, semantic_loss

    precompute_kernel<<<2, 256, 0, stream>>>(E, W1, b1, W2, b2, Cnp, P);
    vq_main_kernel<<<MGRID, TPB, 0, stream>>>(z, E, Cnp, P, w2v,
                                              out_codes, out_codes0, out_zq,
                                              pvq, psem);
    reduce_kernel<<<1, 256, 0, stream>>>(pvq, psem, out_loss);
}

// Round 18
// 586.503 us; speedup vs baseline: 1.3216x; 1.0181x over previous
//
#include <hip/hip_runtime.h>
#include <math.h>

#define NCB 4
#define KC 256
#define DIM 64
#define NTOK (64*4096)            // 262144 tokens
#define TPB 512
#define TOKB 128                  // tokens per block
#define HALF 128                  // codes staged per half
#define MGRID (NTOK/TOKB)         // 2048 blocks

// ---- workspace byte offsets ----
#define WS_C     0            // 4*256*4   = 4096   (np-exact ||e||^2, f32)
#define WS_P     4096         // 256*64*4  = 65536  (semantic pred table)
#define WS_PVQ   69632        // 2048*4 = 8192
#define WS_PSEM  77824        // 2048*4 = 8192

#define ESTRIDE 68            // e_lds row stride in floats (bank decorrelation)

// np pairwise-8 sum of fl(r*r) (separate mul, NO fma)
#define ROWSQ(rr, A) { \
  float p0=rr[0]*rr[0], p1=rr[1]*rr[1], p2=rr[2]*rr[2], p3=rr[3]*rr[3]; \
  float p4=rr[4]*rr[4], p5=rr[5]*rr[5], p6=rr[6]*rr[6], p7=rr[7]*rr[7]; \
  _Pragma("unroll") \
  for (int m_ = 1; m_ < 8; ++m_) { \
    float s0=rr[8*m_+0]*rr[8*m_+0]; p0=p0+s0; float s1=rr[8*m_+1]*rr[8*m_+1]; p1=p1+s1; \
    float s2=rr[8*m_+2]*rr[8*m_+2]; p2=p2+s2; float s3=rr[8*m_+3]*rr[8*m_+3]; p3=p3+s3; \
    float s4=rr[8*m_+4]*rr[8*m_+4]; p4=p4+s4; float s5=rr[8*m_+5]*rr[8*m_+5]; p5=p5+s5; \
    float s6=rr[8*m_+6]*rr[8*m_+6]; p6=p6+s6; float s7=rr[8*m_+7]*rr[8*m_+7]; p7=p7+s7; \
  } \
  A = ((p0+p1) + (p2+p3)) + ((p4+p5) + (p6+p7)); }

// =====================================================================
// Kernel P: np-exact C tables (pairwise-8 sum of e^2) + semantic table
// =====================================================================
__global__ __launch_bounds__(256) void precompute_kernel(
    const float* __restrict__ E,
    const float* __restrict__ W1, const float* __restrict__ b1,
    const float* __restrict__ W2, const float* __restrict__ b2,
    float* __restrict__ Cnp, float* __restrict__ P) {
#pragma clang fp contract(off)
    const int t = threadIdx.x;
    if (blockIdx.x == 0) {
        for (int i = 0; i < NCB; ++i) {
            const float* row = E + (size_t)(i*KC + t)*DIM;
            float e[DIM];
#pragma unroll
            for (int d = 0; d < DIM; ++d) e[d] = row[d];
            float A;
            ROWSQ(e, A);
            Cnp[i*KC + t] = A;
        }
    } else {
        // P[c] = gelu(E0[c]@W1+b1)@W2+b2  (exact erf gelu; tolerance loose)
        const int c = t;
        float e[DIM];
#pragma unroll
        for (int d = 0; d < DIM; ++d) e[d] = E[(size_t)c*DIM + d];
        float h[DIM];
        for (int m = 0; m < DIM; ++m) {
            float acc = b1[m];
            for (int d = 0; d < DIM; ++d) acc = fmaf(e[d], W1[d*DIM + m], acc);
            h[m] = 0.5f * acc * (1.0f + erff(acc * 0.70710678118654752440f));
        }
        for (int n = 0; n < DIM; ++n) {
            float acc = b2[n];
            for (int m = 0; m < DIM; ++m) acc = fmaf(h[m], W2[m*DIM + n], acc);
            P[c*DIM + n] = acc;
        }
    }
}

// =====================================================================
// scan of one staged 128-code half: acc[4][8] register tile, n-dim in
// 2 groups of 4 (e4[4] live) to fit the 64-VGPR (512,4) budget.
// c-loop unroll-1 (round-15 lesson: unrolling hoists loads -> spill).
// FMA chain per acc[m][n] keeps the exact np sgemm order (c ascending,
// x/y/z/w) -> bit-identical.  h==0 saves partial argmin; h==1 merges
// (all half-0 k < all half-1 k -> strict < keeps np first-min).
// ROUND-18: exact revert to the round-14 best (587 us total); rounds
// 15/16/17 falsified unroll-4, m8xn4 retile, and waves_per_eu reg-
// budget raise (toolchain pins 64 VGPR at 16 waves/CU).
// =====================================================================
__device__ __forceinline__ void scan_half(
    const int h, const int i, const int j,
    const float* __restrict__ e_lds, const float* __restrict__ r_lds,
    const float* __restrict__ C_lds, const float* __restrict__ A_lds,
    float* __restrict__ bv1_lds, int* __restrict__ bk1_lds,
    int* __restrict__ bk_out) {
#pragma clang fp contract(off)
    float acc[4][8];
#pragma unroll
    for (int m = 0; m < 4; ++m)
#pragma unroll
        for (int n = 0; n < 8; ++n) acc[m][n] = 0.f;

#pragma unroll 1
    for (int c = 0; c < 16; ++c) {
#pragma unroll
        for (int g = 0; g < 2; ++g) {
            float4 e4[4];
#pragma unroll
            for (int n = 0; n < 4; ++n)
                e4[n] = *(const float4*)&e_lds[ESTRIDE*(j + 16*(4*g + n)) + 4*c];
#pragma unroll
            for (int m = 0; m < 4; ++m) {
                float4 r4 = *(const float4*)&r_lds[(c*TOKB + (i + 32*m))*4];
#pragma unroll
                for (int n = 0; n < 4; ++n) {
                    acc[m][4*g+n] = fmaf(r4.x, e4[n].x, acc[m][4*g+n]);
                    acc[m][4*g+n] = fmaf(r4.y, e4[n].y, acc[m][4*g+n]);
                    acc[m][4*g+n] = fmaf(r4.z, e4[n].z, acc[m][4*g+n]);
                    acc[m][4*g+n] = fmaf(r4.w, e4[n].w, acc[m][4*g+n]);
                }
            }
        }
    }

    float Ck[8];
#pragma unroll
    for (int n = 0; n < 8; ++n) Ck[n] = C_lds[j + 16*n];

#pragma unroll
    for (int m = 0; m < 4; ++m) {
        const float A = A_lds[i + 32*m];
        float bv = INFINITY; int bk = 0;
#pragma unroll
        for (int n = 0; n < 8; ++n) {
            const int k = h*HALF + j + 16*n;        // global code index
            const float x = fmaf(-2.0f, acc[m][n], A) + Ck[n];
            if (x < bv) { bv = x; bk = k; }          // first-min, k asc
        }
#pragma unroll
        for (int s = 8; s >= 1; s >>= 1) {
            const float ov = __shfl_xor(bv, s);
            const int   ok = __shfl_xor(bk, s);
            if (ov < bv || (ov == bv && ok < bk)) { bv = ov; bk = ok; }
        }
        if (j == 0) {
            if (h == 0) { bv1_lds[i + 32*m] = bv; bk1_lds[i + 32*m] = bk; }
            else {
                const float v1 = bv1_lds[i + 32*m];
                const int   k1 = bk1_lds[i + 32*m];
                bk_out[i + 32*m] = (bv < v1) ? bk : k1;
            }
        }
    }
}

// =====================================================================
// Kernel M (FUSED): bit-exact np-f32 argmin chain + z_q_total +
// semantic partials.  512 threads = 32 token-groups x 16 code-groups,
// TOKB=128 tokens/block, codebook staged in TWO 128-code halves
// (LDS 72 KB -> 2 blocks/CU).  __launch_bounds__(512,4): proven 44%
// occupancy (rounds 11/14).  Epilogue = old gather kernel bit-exactly.
// =====================================================================
__global__ __launch_bounds__(TPB, 4) void vq_main_kernel(
    const float* __restrict__ z, const float* __restrict__ Eg,
    const float* __restrict__ Cg, const float* __restrict__ P,
    const float* __restrict__ w2v,
    float* __restrict__ out_codes, float* __restrict__ out_codes0,
    float* __restrict__ out_zq,
    float* __restrict__ partial_vq, float* __restrict__ partial_sem) {
#pragma clang fp contract(off)
    __shared__ float e_lds[HALF*ESTRIDE];   // 34816 B
    __shared__ float r_lds[16*TOKB*4];      // 32768 B, float4 (chunk c, token)
    __shared__ float A_lds[TOKB];           // 512 B
    __shared__ float C_lds[HALF];           // 512 B
    __shared__ int   bkall_lds[NCB][TOKB];  // 2048 B (codes per cb)
    __shared__ float bv1_lds[TOKB];         // 512 B
    __shared__ int   bk1_lds[TOKB];         // 512 B
    __shared__ float red[TPB];              // 2048 B   => total 73728 B

    const int t = threadIdx.x;
    const int j = t & 15;                   // code group
    const int i = t >> 4;                   // token group (0..31)
    const int tokbase = blockIdx.x * TOKB;

    // ---- stage z -> r_lds (transposed: [c][token]) ----
    {
        const int tok = t >> 2;
        const int q0 = (t & 3) * 4;
        const float4* zp = (const float4*)(z + (size_t)(tokbase + tok)*DIM);
#pragma unroll
        for (int c = 0; c < 4; ++c) {
            float4 v = zp[q0 + c];
            *(float4*)&r_lds[((q0 + c)*TOKB + tok)*4] = v;
        }
    }
    __syncthreads();

    float vqacc = 0.f;

#pragma unroll 1
    for (int cb = 0; cb < NCB; ++cb) {
        // ---- A = ||r||^2 (np pairwise-8), current residual ----
        if (t < TOKB) {
            float rr[DIM];
#pragma unroll
            for (int c = 0; c < 16; ++c) {
                float4 v = *(const float4*)&r_lds[(c*TOKB + t)*4];
                rr[4*c+0]=v.x; rr[4*c+1]=v.y; rr[4*c+2]=v.z; rr[4*c+3]=v.w;
            }
            float A;
            ROWSQ(rr, A);
            A_lds[t] = A;
        }

        // ---- half 0: stage codes 0..127 + C, scan ----
        {
            const float* src = Eg + (size_t)cb*KC*DIM;
#pragma unroll
            for (int v = 0; v < 4; ++v) {
                const int idx = t*4 + v;               // 0..2047 float4s
                const int row = idx >> 4, ch = idx & 15;
                *(float4*)&e_lds[ESTRIDE*row + 4*ch] =
                    *(const float4*)(src + row*DIM + 4*ch);
            }
            if (t < HALF) C_lds[t] = Cg[cb*KC + t];
        }
        __syncthreads();
        scan_half(0, i, j, e_lds, r_lds, C_lds, A_lds, bv1_lds, bk1_lds,
                  &bkall_lds[cb][0]);
        __syncthreads();

        // ---- half 1: stage codes 128..255 + C, scan + merge ----
        {
            const float* src = Eg + ((size_t)cb*KC + HALF)*DIM;
#pragma unroll
            for (int v = 0; v < 4; ++v) {
                const int idx = t*4 + v;
                const int row = idx >> 4, ch = idx & 15;
                *(float4*)&e_lds[ESTRIDE*row + 4*ch] =
                    *(const float4*)(src + row*DIM + 4*ch);
            }
            if (t < HALF) C_lds[t] = Cg[cb*KC + HALF + t];
        }
        __syncthreads();
        scan_half(1, i, j, e_lds, r_lds, C_lds, A_lds, bv1_lds, bk1_lds,
                  &bkall_lds[cb][0]);
        __syncthreads();

        // ---- residual update (np-exact straight-through chain),
        //      winning e row from GLOBAL (L2-hot, identical bits) ----
        {
            const int tok = t >> 2;
            const int q0 = (t & 3) * 4;
            const int bk = bkall_lds[cb][tok];
            const float* ep = Eg + ((size_t)cb*KC + bk)*DIM;
#pragma unroll
            for (int c = 0; c < 4; ++c) {
                float* rp = &r_lds[((q0 + c)*TOKB + tok)*4];
                float4 rv = *(const float4*)rp;
                float4 ev = *(const float4*)(ep + 4*(q0 + c));
                float tt, st;
                tt = ev.x - rv.x; vqacc = fmaf(tt,tt,vqacc); st = rv.x + tt; rv.x = rv.x - st;
                tt = ev.y - rv.y; vqacc = fmaf(tt,tt,vqacc); st = rv.y + tt; rv.y = rv.y - st;
                tt = ev.z - rv.z; vqacc = fmaf(tt,tt,vqacc); st = rv.z + tt; rv.z = rv.z - st;
                tt = ev.w - rv.w; vqacc = fmaf(tt,tt,vqacc); st = rv.w + tt; rv.w = rv.w - st;
                *(float4*)rp = rv;
            }
        }
        __syncthreads();
    }

    // ================= fused epilogue (old gather kernel) =============
    float sem = 0.f;
    {
        const int tok = t >> 2;
        const int q0 = (t & 3) * 4;
        const int gtok = tokbase + tok;
        const int c0 = bkall_lds[0][tok], c1 = bkall_lds[1][tok];
        const int c2 = bkall_lds[2][tok], c3 = bkall_lds[3][tok];

        if ((t & 3) == 0) {
            *(float4*)(out_codes + (size_t)gtok*4) =
                make_float4((float)c0, (float)c1, (float)c2, (float)c3);
            out_codes0[gtok] = (float)c0;
        }

        const float4* zp = (const float4*)(z + (size_t)gtok*DIM);
        const float4* e0 = (const float4*)(Eg + (size_t)(0*KC + c0)*DIM);
        const float4* e1 = (const float4*)(Eg + (size_t)(1*KC + c1)*DIM);
        const float4* e2 = (const float4*)(Eg + (size_t)(2*KC + c2)*DIM);
        const float4* e3 = (const float4*)(Eg + (size_t)(3*KC + c3)*DIM);
        float4* o = (float4*)(out_zq + (size_t)gtok*DIM);
        const float4* pp = (const float4*)(P + (size_t)c0*DIM);
        const float4* wv = (const float4*)(w2v + (size_t)gtok*DIM);

#pragma unroll
        for (int q = q0; q < q0 + 4; ++q) {
            float4 zv = zp[q], a = e0[q], b = e1[q], c = e2[q], d = e3[q];
            float4 out;
            {
                float rr, tt, st, tot;
                rr = zv.x;
                tt = a.x - rr; st = rr + tt; tot = st;        rr = rr - st;
                tt = b.x - rr; st = rr + tt; tot = tot + st;  rr = rr - st;
                tt = c.x - rr; st = rr + tt; tot = tot + st;  rr = rr - st;
                tt = d.x - rr; st = rr + tt; tot = tot + st;
                out.x = tot;
            }
            {
                float rr, tt, st, tot;
                rr = zv.y;
                tt = a.y - rr; st = rr + tt; tot = st;        rr = rr - st;
                tt = b.y - rr; st = rr + tt; tot = tot + st;  rr = rr - st;
                tt = c.y - rr; st = rr + tt; tot = tot + st;  rr = rr - st;
                tt = d.y - rr; st = rr + tt; tot = tot + st;
                out.y = tot;
            }
            {
                float rr, tt, st, tot;
                rr = zv.z;
                tt = a.z - rr; st = rr + tt; tot = st;        rr = rr - st;
                tt = b.z - rr; st = rr + tt; tot = tot + st;  rr = rr - st;
                tt = c.z - rr; st = rr + tt; tot = tot + st;  rr = rr - st;
                tt = d.z - rr; st = rr + tt; tot = tot + st;
                out.z = tot;
            }
            {
                float rr, tt, st, tot;
                rr = zv.w;
                tt = a.w - rr; st = rr + tt; tot = st;        rr = rr - st;
                tt = b.w - rr; st = rr + tt; tot = tot + st;  rr = rr - st;
                tt = c.w - rr; st = rr + tt; tot = tot + st;  rr = rr - st;
                tt = d.w - rr; st = rr + tt; tot = tot + st;
                out.w = tot;
            }
            o[q] = out;

            float4 pv = pp[q], wvv = wv[q];
            float df;
            df = pv.x - wvv.x; sem = fmaf(df, df, sem);
            df = pv.y - wvv.y; sem = fmaf(df, df, sem);
            df = pv.z - wvv.z; sem = fmaf(df, df, sem);
            df = pv.w - wvv.w; sem = fmaf(df, df, sem);
        }
    }

    // deterministic block reductions: vq partial, then sem partial
    red[t] = vqacc;
    __syncthreads();
    for (int off = TPB/2; off > 0; off >>= 1) {
        if (t < off) red[t] += red[t + off];
        __syncthreads();
    }
    if (t == 0) partial_vq[blockIdx.x] = red[0];
    __syncthreads();
    red[t] = sem;
    __syncthreads();
    for (int off = TPB/2; off > 0; off >>= 1) {
        if (t < off) red[t] += red[t + off];
        __syncthreads();
    }
    if (t == 0) partial_sem[blockIdx.x] = red[0];
}

// =====================================================================
// Kernel R: deterministic final reduction -> loss scalars
// =====================================================================
__global__ __launch_bounds__(256) void reduce_kernel(
    const float* __restrict__ pvq, const float* __restrict__ psem,
    float* __restrict__ out_loss) {
    __shared__ float sv[256], ss[256];
    const int t = threadIdx.x;
    float a = 0.f, b = 0.f;
    for (int x = t; x < MGRID; x += 256) { a += pvq[x]; b += psem[x]; }
    sv[t] = a; ss[t] = b;
    __syncthreads();
    for (int off = 128; off > 0; off >>= 1) {
        if (t < off) { sv[t] += sv[t+off]; ss[t] += ss[t+off]; }
        __syncthreads();
    }
    if (t == 0) {
        // vq_loss = sum_i (1+0.25)*mean(t^2); semantic = mean((pred-w2v)^2)
        out_loss[0] = 1.25f * sv[0] / 16777216.0f;
        out_loss[1] = ss[0] / 16777216.0f;
    }
}

extern "C" void kernel_launch(void* const* d_in, const int* in_sizes, int n_in,
                              void* d_out, int out_size, void* d_ws, size_t ws_size,
                              hipStream_t stream) {
    (void)in_sizes; (void)n_in; (void)out_size; (void)ws_size;
    const float* z   = (const float*)d_in[0];
    const float* w2v = (const float*)d_in[1];
    const float* E   = (const float*)d_in[2];
    const float* W1  = (const float*)d_in[3];
    const float* b1  = (const float*)d_in[4];
    const float* W2  = (const float*)d_in[5];
    const float* b2  = (const float*)d_in[6];

    float* out = (float*)d_out;
    char*  ws  = (char*)d_ws;
    float* Cnp  = (float*)(ws + WS_C);
    float* P    = (float*)(ws + WS_P);
    float* pvq  = (float*)(ws + WS_PVQ);
    float* psem = (float*)(ws + WS_PSEM);

    float* out_zq     = out;                        // [B,T,64]
    float* out_codes  = out + 16777216;             // [B,T,4]
    float* out_codes0 = out + 17825792;             // [B,T]
    float* out_loss   = out + 18087936;             // vq_loss, semantic_loss

    precompute_kernel<<<2, 256, 0, stream>>>(E, W1, b1, W2, b2, Cnp, P);
    vq_main_kernel<<<MGRID, TPB, 0, stream>>>(z, E, Cnp, P, w2v,
                                              out_codes, out_codes0, out_zq,
                                              pvq, psem);
    reduce_kernel<<<1, 256, 0, stream>>>(pvq, psem, out_loss);
}